// Round 7
// baseline (218.071 us; speedup 1.0000x reference)
//
#include <hip/hip_runtime.h>
#include <math.h>

#define NBATCH 4
#define TDIM 2048
#define DDIM 1024

typedef __attribute__((ext_vector_type(8))) short short8;     // 8 bf16 MFMA frag
typedef __attribute__((ext_vector_type(4))) float floatx4;    // MFMA acc
typedef __attribute__((ext_vector_type(4))) unsigned short ushort4v;

__device__ __forceinline__ unsigned short f2bf(float f) {
  unsigned int u = __float_as_uint(f);
  u += 0x7fffu + ((u >> 16) & 1u);   // round-to-nearest-even
  return (unsigned short)(u >> 16);
}

// async 16B global -> LDS (HW places lane i at lds_base + i*16)
__device__ __forceinline__ void gload_lds16(const ushort* g, ushort* l) {
  __builtin_amdgcn_global_load_lds(
      (const __attribute__((address_space(1))) void*)g,
      (__attribute__((address_space(3))) void*)l, 16, 0, 0);
}

// bijective XCD-chunked block swizzle (nwg % 8 == 0)
__device__ __forceinline__ int xcd_swz(int lin, int nwg) {
  return (lin & 7) * (nwg >> 3) + (lin >> 3);
}

// ---------------------------------------------------------------------------
// 128x128 core (proven, kept for pv_gemm). Conflict-free XOR-8 swizzle.
// ---------------------------------------------------------------------------
__device__ __forceinline__ void mfma_gemm_core(
    const ushort* __restrict__ Abase, const ushort* __restrict__ Bbase,
    int lda, int ldb, int K, ushort* As, ushort* Bs, floatx4 acc[4][4]) {
  const int tid = threadIdx.x;
  const int wave = tid >> 6;
  const int lane = tid & 63;
  const int l15 = lane & 15;
  const int quad = lane >> 4;
  const int wm = wave >> 1, wn = wave & 1;

  const int srow = wave * 32 + (lane >> 3);
  const int schunk = (lane & 7) ^ ((lane >> 3) & 7);
  const ushort* ag = Abase + (size_t)srow * lda + schunk * 8;
  const ushort* bg = Bbase + (size_t)srow * ldb + schunk * 8;
  ushort* al = As + wave * 32 * 64;
  ushort* bl = Bs + wave * 32 * 64;

  const int slot = quad ^ (l15 & 7);
  const int abase = (wm * 64 + l15) * 64 + slot * 8;
  const int bbase = (wn * 64 + l15) * 64 + slot * 8;

  for (int kt = 0; kt < K; kt += 64) {
#pragma unroll
    for (int i = 0; i < 4; ++i) {
      gload_lds16(ag + kt + (size_t)(8 * i) * lda, al + 8 * i * 64);
      gload_lds16(bg + kt + (size_t)(8 * i) * ldb, bl + 8 * i * 64);
    }
    __syncthreads();
#pragma unroll
    for (int g = 0; g < 2; ++g) {
      const int ab = abase ^ (g * 32);
      const int bb = bbase ^ (g * 32);
      short8 af[4], bfr[4];
#pragma unroll
      for (int t = 0; t < 4; ++t) {
        af[t] = *(const short8*)&As[ab + t * 1024];
        bfr[t] = *(const short8*)&Bs[bb + t * 1024];
      }
#pragma unroll
      for (int i = 0; i < 4; ++i)
#pragma unroll
        for (int j = 0; j < 4; ++j)
          acc[i][j] =
              __builtin_amdgcn_mfma_f32_16x16x32_bf16(af[i], bfr[j], acc[i][j], 0, 0, 0);
    }
    __syncthreads();
  }
}

// ---------------------------------------------------------------------------
// R7 core: 256x256, BK=64, double-buffered, depth-3 prefetch.
// 512 threads = 8 waves (2M x 4N); per-wave 128x64 = 8x4 frags; fragments
// read ONCE per K-tile (12/4/8/0 per phase). Stage order A0,B0,B1,A1 with
// READ-MATCHED half-tiles:
//   A-half mh = rows {mh*64+[0,64), 128+mh*64+[0,64)}   (what phases mh read)
//   B-half nh = rows {c*64 + nh*32 + [0,32), c=0..3}    (what phases nh read)
// Issue->first-read distance: A0:4, B0:3, B1:3, A1:3 phases (~1650cyc > HBM
// ~900cyc).  Uniform vmcnt(4) before the barrier at each read-phase entry
// (P0,P1,P2) retires exactly the half-tile(s) that phase reads; peeled last
// tile uses 4/2/0.  One barrier per read-phase (3/K-tile).  This fixes R2's
// two diagnosed flaws (1-phase cover at p3; B stage/read half mismatch).
// ---------------------------------------------------------------------------
__device__ __forceinline__ void stage_A_half(const ushort* A, int lda, int kt,
                                             ushort* As, int mh, int w, int lane) {
#pragma unroll
  for (int i = 0; i < 2; ++i) {
    const int g = w * 2 + i;                                // 0..15
    const int rb = mh * 64 + (g & 7) * 8 + (g >> 3) * 128;  // 8-row group base
    const int r = rb + (lane >> 3);
    const int c = (lane & 7) ^ ((lane >> 3) & 7);
    gload_lds16(A + (size_t)r * lda + kt + c * 8, As + rb * 64);
  }
}

__device__ __forceinline__ void stage_B_half(const ushort* B, int ldb, int kt,
                                             ushort* Bs, int nh, int w, int lane) {
#pragma unroll
  for (int i = 0; i < 2; ++i) {
    const int g = w * 2 + i;                                // 0..15
    const int rb = (g >> 2) * 64 + nh * 32 + (g & 3) * 8;   // read-matched rows
    const int r = rb + (lane >> 3);
    const int c = (lane & 7) ^ ((lane >> 3) & 7);
    gload_lds16(B + (size_t)r * ldb + kt + c * 8, Bs + rb * 64);
  }
}

__device__ __forceinline__ void mfma_core256d3(
    const ushort* __restrict__ A, const ushort* __restrict__ B, int lda,
    int ldb, int K, ushort* As0, ushort* As1, ushort* Bs0, ushort* Bs1,
    floatx4 acc[8][4]) {
  const int tid = threadIdx.x;
  const int w = tid >> 6, lane = tid & 63;
  const int l15 = lane & 15, quad = lane >> 4;
  const int wm = w >> 2, wn = w & 3;
  const int slot = (quad ^ (l15 & 7)) * 8;
  const int abase = (wm * 128 + l15) * 64 + slot;
  const int bbase = (wn * 64 + l15) * 64 + slot;
  const int NT = K >> 6;

  // prologue: tile 0, issue order A0,B0,B1,A1 (matches read order)
  stage_A_half(A, lda, 0, As0, 0, w, lane);
  stage_B_half(B, ldb, 0, Bs0, 0, w, lane);
  stage_B_half(B, ldb, 0, Bs0, 1, w, lane);
  stage_A_half(A, lda, 0, As0, 1, w, lane);

  const ushort* cA = As0;
  const ushort* cB = Bs0;
  ushort* nA = As1;
  ushort* nB = Bs1;
  short8 af[4][2], bf0[2][2], bf1[2][2];

#pragma unroll 1
  for (int t = 0; t < NT - 1; ++t) {
    const int ktn = (t + 1) << 6;
    // ---- P0: wait A0,B0(t); reads A-m0 + B-n0; stage A0(t+1); MFMA (m0,n0)
    asm volatile("s_waitcnt vmcnt(4)" ::: "memory");
    __builtin_amdgcn_s_barrier();
#pragma unroll
    for (int f = 0; f < 4; ++f)
#pragma unroll
      for (int g = 0; g < 2; ++g)
        af[f][g] = *(const short8*)&cA[(abase + f * 1024) ^ (g * 32)];
#pragma unroll
    for (int f = 0; f < 2; ++f)
#pragma unroll
      for (int g = 0; g < 2; ++g)
        bf0[f][g] = *(const short8*)&cB[(bbase + f * 1024) ^ (g * 32)];
    stage_A_half(A, lda, ktn, nA, 0, w, lane);
    __builtin_amdgcn_s_setprio(1);
#pragma unroll
    for (int f = 0; f < 4; ++f)
#pragma unroll
      for (int fj = 0; fj < 2; ++fj)
#pragma unroll
        for (int g = 0; g < 2; ++g)
          acc[f][fj] = __builtin_amdgcn_mfma_f32_16x16x32_bf16(
              af[f][g], bf0[fj][g], acc[f][fj], 0, 0, 0);
    __builtin_amdgcn_s_setprio(0);
    // ---- P1: wait B1(t); reads B-n1; stage B0(t+1); MFMA (m0,n1)
    asm volatile("s_waitcnt vmcnt(4)" ::: "memory");
    __builtin_amdgcn_s_barrier();
#pragma unroll
    for (int f = 0; f < 2; ++f)
#pragma unroll
      for (int g = 0; g < 2; ++g)
        bf1[f][g] = *(const short8*)&cB[(bbase + 2048 + f * 1024) ^ (g * 32)];
    stage_B_half(B, ldb, ktn, nB, 0, w, lane);
    __builtin_amdgcn_s_setprio(1);
#pragma unroll
    for (int f = 0; f < 4; ++f)
#pragma unroll
      for (int fj = 0; fj < 2; ++fj)
#pragma unroll
        for (int g = 0; g < 2; ++g)
          acc[f][2 + fj] = __builtin_amdgcn_mfma_f32_16x16x32_bf16(
              af[f][g], bf1[fj][g], acc[f][2 + fj], 0, 0, 0);
    __builtin_amdgcn_s_setprio(0);
    // ---- P2: wait A1(t); reads A-m1 (overwrite af); stage B1(t+1); MFMA (m1,n0)
    asm volatile("s_waitcnt vmcnt(4)" ::: "memory");
    __builtin_amdgcn_s_barrier();
#pragma unroll
    for (int f = 0; f < 4; ++f)
#pragma unroll
      for (int g = 0; g < 2; ++g)
        af[f][g] = *(const short8*)&cA[(abase + 4096 + f * 1024) ^ (g * 32)];
    stage_B_half(B, ldb, ktn, nB, 1, w, lane);
    __builtin_amdgcn_s_setprio(1);
#pragma unroll
    for (int f = 0; f < 4; ++f)
#pragma unroll
      for (int fj = 0; fj < 2; ++fj)
#pragma unroll
        for (int g = 0; g < 2; ++g)
          acc[4 + f][fj] = __builtin_amdgcn_mfma_f32_16x16x32_bf16(
              af[f][g], bf0[fj][g], acc[4 + f][fj], 0, 0, 0);
    __builtin_amdgcn_s_setprio(0);
    // ---- P3: no reads, no wait, no barrier; stage A1(t+1); MFMA (m1,n1)
    stage_A_half(A, lda, ktn, nA, 1, w, lane);
    __builtin_amdgcn_s_setprio(1);
#pragma unroll
    for (int f = 0; f < 4; ++f)
#pragma unroll
      for (int fj = 0; fj < 2; ++fj)
#pragma unroll
        for (int g = 0; g < 2; ++g)
          acc[4 + f][2 + fj] = __builtin_amdgcn_mfma_f32_16x16x32_bf16(
              af[f][g], bf1[fj][g], acc[4 + f][2 + fj], 0, 0, 0);
    __builtin_amdgcn_s_setprio(0);

    ushort* tmp = nA; nA = (ushort*)cA; cA = tmp;
    tmp = nB; nB = (ushort*)cB; cB = tmp;
  }

  // ---- peeled last tile: waits 4/2/0, no staging
  asm volatile("s_waitcnt vmcnt(4)" ::: "memory");
  __builtin_amdgcn_s_barrier();
#pragma unroll
  for (int f = 0; f < 4; ++f)
#pragma unroll
    for (int g = 0; g < 2; ++g)
      af[f][g] = *(const short8*)&cA[(abase + f * 1024) ^ (g * 32)];
#pragma unroll
  for (int f = 0; f < 2; ++f)
#pragma unroll
    for (int g = 0; g < 2; ++g)
      bf0[f][g] = *(const short8*)&cB[(bbase + f * 1024) ^ (g * 32)];
  __builtin_amdgcn_s_setprio(1);
#pragma unroll
  for (int f = 0; f < 4; ++f)
#pragma unroll
    for (int fj = 0; fj < 2; ++fj)
#pragma unroll
      for (int g = 0; g < 2; ++g)
        acc[f][fj] = __builtin_amdgcn_mfma_f32_16x16x32_bf16(
            af[f][g], bf0[fj][g], acc[f][fj], 0, 0, 0);
  __builtin_amdgcn_s_setprio(0);
  asm volatile("s_waitcnt vmcnt(2)" ::: "memory");
  __builtin_amdgcn_s_barrier();
#pragma unroll
  for (int f = 0; f < 2; ++f)
#pragma unroll
    for (int g = 0; g < 2; ++g)
      bf1[f][g] = *(const short8*)&cB[(bbase + 2048 + f * 1024) ^ (g * 32)];
  __builtin_amdgcn_s_setprio(1);
#pragma unroll
  for (int f = 0; f < 4; ++f)
#pragma unroll
    for (int fj = 0; fj < 2; ++fj)
#pragma unroll
      for (int g = 0; g < 2; ++g)
        acc[f][2 + fj] = __builtin_amdgcn_mfma_f32_16x16x32_bf16(
            af[f][g], bf1[fj][g], acc[f][2 + fj], 0, 0, 0);
  __builtin_amdgcn_s_setprio(0);
  asm volatile("s_waitcnt vmcnt(0)" ::: "memory");
  __builtin_amdgcn_s_barrier();
#pragma unroll
  for (int f = 0; f < 4; ++f)
#pragma unroll
    for (int g = 0; g < 2; ++g)
      af[f][g] = *(const short8*)&cA[(abase + 4096 + f * 1024) ^ (g * 32)];
  __builtin_amdgcn_s_setprio(1);
#pragma unroll
  for (int f = 0; f < 4; ++f)
#pragma unroll
    for (int fj = 0; fj < 2; ++fj)
#pragma unroll
      for (int g = 0; g < 2; ++g)
        acc[4 + f][fj] = __builtin_amdgcn_mfma_f32_16x16x32_bf16(
            af[f][g], bf0[fj][g], acc[4 + f][fj], 0, 0, 0);
#pragma unroll
  for (int f = 0; f < 4; ++f)
#pragma unroll
    for (int fj = 0; fj < 2; ++fj)
#pragma unroll
      for (int g = 0; g < 2; ++g)
        acc[4 + f][2 + fj] = __builtin_amdgcn_mfma_f32_16x16x32_bf16(
            af[f][g], bf1[fj][g], acc[4 + f][2 + fj], 0, 0, 0);
  __builtin_amdgcn_s_setprio(0);
}

// ---------------------------------------------------------------------------
// Fused converts (unchanged).
// ---------------------------------------------------------------------------
__global__ __launch_bounds__(256) void convert_xw(
    const float* __restrict__ x, const float* __restrict__ W,
    ushort* __restrict__ xb, ushort* __restrict__ wb) {
  const int bid = blockIdx.x;
  if (bid < 8192) {
    const size_t i = (size_t)bid * 256 + threadIdx.x;  // float4 index
    float4 v = reinterpret_cast<const float4*>(x)[i];
    ushort4v h = {f2bf(v.x), f2bf(v.y), f2bf(v.z), f2bf(v.w)};
    reinterpret_cast<ushort4v*>(xb)[i] = h;
  } else {
    const int e = bid - 8192;
    const int c = e % 3, ii = e / 3;
    const float scale = (c == 0) ? 0.03125f : 1.0f;
    const float4 v = reinterpret_cast<const float4*>(W + (size_t)e * DDIM)[threadIdx.x];
    ushort4v h = {f2bf(v.x * scale), f2bf(v.y * scale), f2bf(v.z * scale),
                  f2bf(v.w * scale)};
    reinterpret_cast<ushort4v*>(wb + (size_t)(c * DDIM + ii) * DDIM)[threadIdx.x] = h;
  }
}

// ---------------------------------------------------------------------------
// QKV on the depth-3 256x256 core. Grid 384 blocks (12 x 32), 512 threads.
// ---------------------------------------------------------------------------
__global__ __launch_bounds__(512, 2) void qkv_gemm8(
    const ushort* __restrict__ xb, const ushort* __restrict__ wb,
    ushort* __restrict__ qb, ushort* __restrict__ kb, ushort* __restrict__ vt) {
  __shared__ __align__(16) ushort As0[256 * 64], As1[256 * 64];
  __shared__ __align__(16) ushort Bs0[256 * 64], Bs1[256 * 64];
  const int swz = xcd_swz(blockIdx.x, 384);
  const int bx = swz % 12, by = swz / 12;
  const int m0 = by * 256;
  const int n0 = bx * 256;
  floatx4 acc[8][4];
  const floatx4 z4 = {0.f, 0.f, 0.f, 0.f};
#pragma unroll
  for (int i = 0; i < 8; ++i)
#pragma unroll
    for (int j = 0; j < 4; ++j) acc[i][j] = z4;

  mfma_core256d3(xb + (size_t)m0 * DDIM, wb + (size_t)n0 * DDIM, DDIM, DDIM,
                 DDIM, As0, As1, Bs0, Bs1, acc);

  const int tid = threadIdx.x;
  const int w = tid >> 6, lane = tid & 63;
  const int l15 = lane & 15, quad = lane >> 4;
  const int wm = w >> 2, wn = w & 3;

  if (n0 < 2 * DDIM) {
    ushort* dst = (n0 < DDIM) ? qb : kb;
    const int cb = (n0 < DDIM) ? n0 : n0 - DDIM;
#pragma unroll
    for (int i = 0; i < 8; ++i) {
      const int rbase = m0 + wm * 128 + i * 16 + quad * 4;
#pragma unroll
      for (int j = 0; j < 4; ++j) {
        const int col = cb + wn * 64 + j * 16 + l15;
#pragma unroll
        for (int r = 0; r < 4; ++r)
          dst[(size_t)(rbase + r) * DDIM + col] = f2bf(acc[i][j][r]);
      }
    }
  } else {
#pragma unroll
    for (int i = 0; i < 8; ++i) {
      const int row = m0 + wm * 128 + i * 16 + quad * 4;  // 4 consecutive t
      const int b = row >> 11, t = row & (TDIM - 1);
#pragma unroll
      for (int j = 0; j < 4; ++j) {
        const int d = (n0 - 2 * DDIM) + wn * 64 + j * 16 + l15;
        ushort4v pk = {f2bf(acc[i][j][0]), f2bf(acc[i][j][1]),
                       f2bf(acc[i][j][2]), f2bf(acc[i][j][3])};
        *reinterpret_cast<ushort4v*>(&vt[(size_t)((b << 10) + d) * TDIM + t]) = pk;
      }
    }
  }
}

// ---------------------------------------------------------------------------
// Score on the depth-3 256x256 core. Grid 256 blocks (8 x 8 x 4) = exactly
// one residency round at 1 block/CU. P_unnorm = exp(q_scaled.k) bf16;
// per-row partial sums of this 256-col tile to lpart[(z*8 + bx)*2048 + row].
// ---------------------------------------------------------------------------
__global__ __launch_bounds__(512, 2) void score_gemm8(
    const ushort* __restrict__ qb, const ushort* __restrict__ kb,
    ushort* __restrict__ Sb, float* __restrict__ lpart) {
  __shared__ __align__(16) ushort As0[256 * 64], As1[256 * 64];
  __shared__ __align__(16) ushort Bs0[256 * 64], Bs1[256 * 64];
  const int swz = xcd_swz(blockIdx.x, 256);
  const int bx = swz & 7, by = (swz >> 3) & 7, z = swz >> 6;
  const int m0 = by * 256;
  const int n0 = bx * 256;
  floatx4 acc[8][4];
  const floatx4 z4 = {0.f, 0.f, 0.f, 0.f};
#pragma unroll
  for (int i = 0; i < 8; ++i)
#pragma unroll
    for (int j = 0; j < 4; ++j) acc[i][j] = z4;

  mfma_core256d3(qb + ((size_t)z * TDIM + m0) * DDIM,
                 kb + ((size_t)z * TDIM + n0) * DDIM, DDIM, DDIM, DDIM, As0,
                 As1, Bs0, Bs1, acc);

  const int tid = threadIdx.x;
  const int w = tid >> 6, lane = tid & 63;
  const int l15 = lane & 15, quad = lane >> 4;
  const int wm = w >> 2, wn = w & 3;

  ushort* S = Sb + (size_t)z * TDIM * TDIM;
#pragma unroll
  for (int i = 0; i < 8; ++i)
#pragma unroll
    for (int j = 0; j < 4; ++j)
#pragma unroll
      for (int r = 0; r < 4; ++r) acc[i][j][r] = __expf(acc[i][j][r]);

#pragma unroll
  for (int i = 0; i < 8; ++i) {
    const int rbase = m0 + wm * 128 + i * 16 + quad * 4;
#pragma unroll
    for (int j = 0; j < 4; ++j) {
      const int col = n0 + wn * 64 + j * 16 + l15;
#pragma unroll
      for (int r = 0; r < 4; ++r)
        S[(size_t)(rbase + r) * TDIM + col] = f2bf(acc[i][j][r]);
    }
  }

  // per-row sums: j-reduce, 16-lane quad-group reduce, combine 4 wn waves
  float* sums = reinterpret_cast<float*>(As0);  // [256][4], free after core
  __syncthreads();
#pragma unroll
  for (int i = 0; i < 8; ++i) {
#pragma unroll
    for (int r = 0; r < 4; ++r) {
      float s = acc[i][0][r] + acc[i][1][r] + acc[i][2][r] + acc[i][3][r];
#pragma unroll
      for (int off = 8; off > 0; off >>= 1) s += __shfl_down(s, off, 16);
      if (l15 == 0) sums[(wm * 128 + i * 16 + quad * 4 + r) * 4 + wn] = s;
    }
  }
  __syncthreads();
  if (tid < 256)
    lpart[((size_t)z * 8 + bx) * TDIM + m0 + tid] =
        sums[tid * 4] + sums[tid * 4 + 1] + sums[tid * 4 + 2] + sums[tid * 4 + 3];
}

// ---------------------------------------------------------------------------
// PV + normalization (proven 128x128 core; 256^2 grid would be 128 blocks =
// half-idle). l[t] = sum of 8 score-tile partials now.
// ---------------------------------------------------------------------------
__global__ __launch_bounds__(256, 3) void pv_gemm(
    const ushort* __restrict__ Pb, const ushort* __restrict__ vt,
    const float* __restrict__ lpart, float* __restrict__ out) {
  __shared__ __align__(16) ushort As[128 * 64];
  __shared__ __align__(16) ushort Bs[128 * 64];
  const int swz = xcd_swz(blockIdx.x, 512);
  const int bx = swz & 7, by = (swz >> 3) & 15, z = swz >> 7;
  const int m0 = by * 128;
  const int n0 = bx * 128;
  floatx4 acc[4][4];
  const floatx4 z4 = {0.f, 0.f, 0.f, 0.f};
#pragma unroll
  for (int i = 0; i < 4; ++i)
#pragma unroll
    for (int j = 0; j < 4; ++j) acc[i][j] = z4;

  mfma_gemm_core(Pb + (size_t)z * TDIM * TDIM + (size_t)m0 * TDIM,
                 vt + (size_t)z * DDIM * TDIM + (size_t)n0 * TDIM, TDIM, TDIM,
                 TDIM, As, Bs, acc);

  const int tid = threadIdx.x;
  const int wave = tid >> 6, lane = tid & 63;
  const int l15 = lane & 15, quad = lane >> 4;
  const int wm = wave >> 1, wn = wave & 1;

  float* linv = reinterpret_cast<float*>(As);  // [128], As free after core
  __syncthreads();
  if (tid < 128) {
    float s = 0.f;
#pragma unroll
    for (int nb = 0; nb < 8; ++nb)
      s += lpart[((size_t)z * 8 + nb) * TDIM + m0 + tid];
    linv[tid] = 1.0f / s;
  }
  __syncthreads();

  float* O = out + (size_t)z * TDIM * DDIM;
#pragma unroll
  for (int i = 0; i < 4; ++i) {
    const int rl = wm * 64 + i * 16 + quad * 4;
    const int rbase = m0 + rl;
#pragma unroll
    for (int j = 0; j < 4; ++j) {
      const int col = n0 + wn * 64 + j * 16 + l15;
#pragma unroll
      for (int r = 0; r < 4; ++r)
        O[(size_t)(rbase + r) * DDIM + col] = acc[i][j][r] * linv[rl + r];
    }
  }
}

// ---------------------------------------------------------------------------
extern "C" void kernel_launch(void* const* d_in, const int* in_sizes, int n_in,
                              void* d_out, int out_size, void* d_ws, size_t ws_size,
                              hipStream_t stream) {
  const float* x = (const float*)d_in[0];  // [4,2048,1024] fp32
  const float* W = (const float*)d_in[1];  // [3072,1024] fp32
  float* out = (float*)d_out;              // [4,2048,1024] fp32

  ushort* ws = (ushort*)d_ws;
  const size_t n_x = (size_t)NBATCH * TDIM * DDIM;  // 8.39M
  const size_t n_w = (size_t)3 * DDIM * DDIM;       // 3.15M
  ushort* xb = ws;        // 16.8 MB
  ushort* wb = xb + n_x;  // 6.3 MB (rows permuted q|k|v, q pre-scaled 1/32)
  ushort* qb = wb + n_w;  // 16.8 MB [b*t][d]
  ushort* kb = qb + n_x;  // 16.8 MB [b*t][d]
  ushort* vt = kb + n_x;  // 16.8 MB [b][d][t]
  ushort* Sb = vt + n_x;  // 33.5 MB [b][t][t] bf16 unnormalized exp(scores)
  float* lpart = (float*)(Sb + (size_t)NBATCH * TDIM * TDIM);  // 256 KB

  convert_xw<<<dim3(8192 + 3 * DDIM), 256, 0, stream>>>(x, W, xb, wb);
  qkv_gemm8<<<dim3(384), 512, 0, stream>>>(xb, wb, qb, kb, vt);
  score_gemm8<<<dim3(256), 512, 0, stream>>>(qb, kb, Sb, lpart);
  pv_gemm<<<dim3(512), 256, 0, stream>>>(Sb, vt, lpart, out);
}